// Round 25
// baseline (52.372 us; speedup 1.0000x reference)
//
#include <hip/hip_runtime.h>
#include <hip/hip_bf16.h>

#define NROWS 16384   // B*S
#define KD    2048    // D
#define NE    16      // experts
#define ROWS_PER_BLK 64
#define KH    1024    // K-half resident in LDS
#define TPH   16      // tiles of 64 K-floats per half

// v22 = v21 (barrier-free, 48.7us) at 16 waves/block for 4 waves/SIMD TLP.
//  - block = 1024 thr / 16 waves / 64 rows; grid 256 = 1 block/CU
//  - wave w -> (expert-pair ep=w&7, row-half rh=w>>3); x-dup 8x (L1-served)
//  - lane = (rgrp=lane>>3 -> 4 rows, seg=lane&7); acc = 16 floats
//  - W K-half [32][1024] = 128 KB resident in LDS; staged twice; 5 barriers total
//  - main loop: pure XLOAD + ds_read + FMA, zero barriers
// Output FLOAT32: [262144 probs][32768 ids-as-floats].

__device__ __forceinline__ void gload_lds16(const float* g, float* l) {
    __builtin_amdgcn_global_load_lds(
        (const __attribute__((address_space(1))) void*)g,
        (__attribute__((address_space(3))) void*)l,
        16, 0, 0);
}

__global__ __launch_bounds__(1024)
void noisy_router_kernel(const float* __restrict__ x,
                         const float* __restrict__ noise,
                         const float* __restrict__ Wfc,
                         const float* __restrict__ bfc,
                         const float* __restrict__ Wns,
                         const float* __restrict__ bns,
                         float* __restrict__ out)
{
    // [0, 32768): W-half [32 rows][1024];  [32768, 34880): epilogue slab [64][33]
    __shared__ float lds[32 * KH + ROWS_PER_BLK * 33];   // 139.5 KB

    const int tid  = threadIdx.x;
    const int lane = tid & 63;
    const int w    = tid >> 6;     // 0..15
    const int ep   = w & 7;        // expert pair 0..7
    const int rh   = w >> 3;       // row half 0..1
    const int seg  = lane & 7;
    const int rgrp = lane >> 3;

    const int rowbase = blockIdx.x * ROWS_PER_BLK + rh * 32 + rgrp * 4;

    // staging map: instr i (0..7) writes W-stack rows {4i..4i+3}:
    // thread tid -> row 4i + (tid>>8), col (tid&255)*4; dest = i*16KB + tid*16B
    // (uniform base + lane*16: legal form). Rows 0..15 = Wfc, 16..31 = Wns.
    const int wrb  = tid >> 8;             // 0..3
    const int scol = (tid & 255) * 4;

    const float* xb = x + (size_t)rowbase * KD + seg * 8;

    float accA[4][2], accB[4][2];          // [row j][expert e] -- 16 floats
    #pragma unroll
    for (int j = 0; j < 4; ++j)
        #pragma unroll
        for (int e = 0; e < 2; ++e) { accA[j][e] = 0.f; accB[j][e] = 0.f; }

    #pragma unroll 1
    for (int h = 0; h < 2; ++h) {
        const int kbase = h * KH;
        __syncthreads();                       // all reads of prev half done
        {
            const float* srcF = Wfc + (size_t)wrb * KD + kbase + scol;   // i = 0..3
            const float* srcN = Wns + (size_t)wrb * KD + kbase + scol;   // i = 4..7
            #pragma unroll
            for (int i = 0; i < 4; ++i)
                gload_lds16(srcF + (size_t)(4 * i) * KD, lds + i * 4096 + tid * 4);
            #pragma unroll
            for (int i = 0; i < 4; ++i)
                gload_lds16(srcN + (size_t)(4 * i) * KD, lds + (4 + i) * 4096 + tid * 4);
        }
        __syncthreads();                       // W-half staged (vmcnt drained)

        const float* wp0 = lds + (ep * 2) * KH + seg * 8;        // Wfc expert rows
        const float* wp1 = lds + (16 + ep * 2) * KH + seg * 8;   // Wns expert rows
        const float* xh  = xb + kbase;

        // ---- 16 tiles, ZERO barriers: compiler free to pipeline loads ----
        #pragma unroll 2
        for (int t = 0; t < TPH; ++t) {
            float4 xv[4][2];
            #pragma unroll
            for (int j = 0; j < 4; ++j) {
                xv[j][0] = *(const float4*)(xh + (size_t)j * KD + t * 64);
                xv[j][1] = *(const float4*)(xh + (size_t)j * KD + t * 64 + 4);
            }
            #pragma unroll
            for (int e = 0; e < 2; ++e) {
                const float4 a0 = *(const float4*)(wp0 + e * KH + t * 64);
                const float4 a1 = *(const float4*)(wp0 + e * KH + t * 64 + 4);
                const float4 b0 = *(const float4*)(wp1 + e * KH + t * 64);
                const float4 b1 = *(const float4*)(wp1 + e * KH + t * 64 + 4);
                #pragma unroll
                for (int j = 0; j < 4; ++j) {
                    const float4 x0 = xv[j][0], x1 = xv[j][1];
                    float sA = accA[j][e], sB = accB[j][e];
                    sA = fmaf(x0.x, a0.x, sA); sA = fmaf(x0.y, a0.y, sA);
                    sA = fmaf(x0.z, a0.z, sA); sA = fmaf(x0.w, a0.w, sA);
                    sA = fmaf(x1.x, a1.x, sA); sA = fmaf(x1.y, a1.y, sA);
                    sA = fmaf(x1.z, a1.z, sA); sA = fmaf(x1.w, a1.w, sA);
                    sB = fmaf(x0.x, b0.x, sB); sB = fmaf(x0.y, b0.y, sB);
                    sB = fmaf(x0.z, b0.z, sB); sB = fmaf(x0.w, b0.w, sB);
                    sB = fmaf(x1.x, b1.x, sB); sB = fmaf(x1.y, b1.y, sB);
                    sB = fmaf(x1.z, b1.z, sB); sB = fmaf(x1.w, b1.w, sB);
                    accA[j][e] = sA; accB[j][e] = sB;
                }
            }
        }
    }

    // ---- butterfly over the 8 k-segs (masks 1,2,4 stay within seg-group) ----
    #pragma unroll
    for (int j = 0; j < 4; ++j)
        #pragma unroll
        for (int e = 0; e < 2; ++e) {
            float a = accA[j][e], b = accB[j][e];
            a += __shfl_xor(a, 1); a += __shfl_xor(a, 2); a += __shfl_xor(a, 4);
            b += __shfl_xor(b, 1); b += __shfl_xor(b, 2); b += __shfl_xor(b, 4);
            accA[j][e] = a; accB[j][e] = b;
        }

    __syncthreads();                  // all W reads done
    float* const slab = lds + 32 * KH;   // [64 rows][stride 33]

    if (seg == 0) {                   // each wave owns (4 rows x expert-pair) outs
        #pragma unroll
        for (int j = 0; j < 4; ++j) {
            float* dst = slab + (rh * 32 + rgrp * 4 + j) * 33 + ep * 2;
            dst[0]  = accA[j][0]; dst[1]  = accA[j][1];
            dst[16] = accB[j][0]; dst[17] = accB[j][1];
        }
    }
    __syncthreads();

    // ---- per-row epilogue: softplus noise, top-2, sparse softmax ----
    if (tid < ROWS_PER_BLK) {
        const int r = tid;
        const float* rowp = slab + r * 33;
        const size_t grow = (size_t)blockIdx.x * ROWS_PER_BLK + r;
        const float* nzp = noise + grow * NE;

        float m1 = -1e30f, m2 = -1e30f;
        int i1 = 0, i2 = 0;
        #pragma unroll
        for (int j = 0; j < NE; ++j) {
            const float z  = rowp[16 + j] + bns[j];
            const float sp = fmaxf(z, 0.f) + log1pf(expf(-fabsf(z)));  // jax softplus
            const float v  = fmaf(nzp[j], sp, rowp[j] + bfc[j]);
            if (v > m1)      { m2 = m1; i2 = i1; m1 = v; i1 = j; }     // ties -> lower idx
            else if (v > m2) { m2 = v;  i2 = j; }
        }
        const float e2  = expf(m2 - m1);
        const float inv = 1.f / (1.f + e2);

        float* po = out + grow * NE;
        #pragma unroll
        for (int j = 0; j < NE; ++j) {
            po[j] = (j == i1) ? inv : ((j == i2) ? e2 * inv : 0.f);
        }
        float* pi = out + (size_t)NROWS * NE + grow * 2;
        pi[0] = (float)i1;
        pi[1] = (float)i2;
    }
}

extern "C" void kernel_launch(void* const* d_in, const int* in_sizes, int n_in,
                              void* d_out, int out_size, void* d_ws, size_t ws_size,
                              hipStream_t stream)
{
    const float* x     = (const float*)d_in[0];
    const float* noise = (const float*)d_in[1];
    const float* Wfc   = (const float*)d_in[2];
    const float* bfc   = (const float*)d_in[3];
    const float* Wns   = (const float*)d_in[4];
    const float* bns   = (const float*)d_in[5];
    float* out = (float*)d_out;

    noisy_router_kernel<<<NROWS / ROWS_PER_BLK, 1024, 0, stream>>>(
        x, noise, Wfc, bfc, Wns, bns, out);
}

// Round 26
// 49.684 us; speedup vs baseline: 1.0541x; 1.0541x over previous
//
#include <hip/hip_runtime.h>
#include <hip/hip_bf16.h>

#define NROWS 16384   // B*S
#define KD    2048    // D
#define NE    16      // experts
#define ROWS_PER_BLK 64
#define KH    1024    // K-half resident in LDS
#define TPH   16      // tiles of 64 K-floats per half

// v23 = v21 (barrier-free, 48.7us champion) + explicit 1-tile x lookahead.
//  - block = 512 thr / 8 waves / 64 rows; grid 256 = 1 block/CU
//  - wave w -> (expert-quartet eq=w&3, row-half rh=w>>2); x-dup 4x (L1-served)
//  - lane = (rgrp=lane>>3 -> 4 rows, seg=lane&7); acc = 32 floats
//  - W K-half [32][1024] = 128 KB resident in LDS; staged twice; 5 barriers total
//  - inner loop: XLOAD(next) issued BEFORE COMPUTE(cur) -> 8 vmem loads in
//    flight under 512cy FMA; ds_read free to schedule (W resident, no dbuf)
//  - xvA/xvB: lexical buffer names, static indices only (no alloca risk)
// Output FLOAT32: [262144 probs][32768 ids-as-floats].

__device__ __forceinline__ void gload_lds16(const float* g, float* l) {
    __builtin_amdgcn_global_load_lds(
        (const __attribute__((address_space(1))) void*)g,
        (__attribute__((address_space(3))) void*)l,
        16, 0, 0);
}

__global__ __launch_bounds__(512)
void noisy_router_kernel(const float* __restrict__ x,
                         const float* __restrict__ noise,
                         const float* __restrict__ Wfc,
                         const float* __restrict__ bfc,
                         const float* __restrict__ Wns,
                         const float* __restrict__ bns,
                         float* __restrict__ out)
{
    // [0, 32768): W-half [32 rows][1024];  [32768, 34880): epilogue slab [64][33]
    __shared__ float lds[32 * KH + ROWS_PER_BLK * 33];   // 139.5 KB

    const int tid  = threadIdx.x;
    const int lane = tid & 63;
    const int w    = tid >> 6;     // 0..7
    const int eq   = w & 3;        // expert quartet 0..3
    const int rh   = w >> 2;       // row half 0..1
    const int seg  = lane & 7;
    const int rgrp = lane >> 3;

    const int rowbase = blockIdx.x * ROWS_PER_BLK + rh * 32 + rgrp * 4;

    // staging map: instr i (0..15) writes W-stack rows {2i, 2i+1}:
    // thread tid -> row 2i + (tid>>8), col (tid&255)*4; dest = i*8KB + tid*16B
    // (uniform base + lane*16: legal form). Rows 0..15 = Wfc, 16..31 = Wns.
    const int wrb  = tid >> 8;             // 0 or 1
    const int scol = (tid & 255) * 4;

    const float* xb = x + (size_t)rowbase * KD + seg * 8;

    float accA[4][4], accB[4][4];          // 32 floats (proven no-spill size)
    #pragma unroll
    for (int j = 0; j < 4; ++j)
        #pragma unroll
        for (int e = 0; e < 4; ++e) { accA[j][e] = 0.f; accB[j][e] = 0.f; }

    float4 xvA[4][2], xvB[4][2];   // two lexically-named x tile buffers

#define XLOAD(XV, T) { _Pragma("unroll")                                   \
    for (int j = 0; j < 4; ++j) {                                          \
        XV[j][0] = *(const float4*)(xh + (size_t)j * KD + (T) * 64);       \
        XV[j][1] = *(const float4*)(xh + (size_t)j * KD + (T) * 64 + 4);   \
    } }

#define COMPUTE(XV, T) { _Pragma("unroll")                                 \
    for (int e = 0; e < 4; ++e) {                                          \
        const float4 a0 = *(const float4*)(wp0 + e * KH + (T) * 64);       \
        const float4 a1 = *(const float4*)(wp0 + e * KH + (T) * 64 + 4);   \
        const float4 b0 = *(const float4*)(wp1 + e * KH + (T) * 64);       \
        const float4 b1 = *(const float4*)(wp1 + e * KH + (T) * 64 + 4);   \
        _Pragma("unroll")                                                  \
        for (int j = 0; j < 4; ++j) {                                      \
            const float4 x0 = XV[j][0], x1 = XV[j][1];                     \
            float sA = accA[j][e], sB = accB[j][e];                        \
            sA = fmaf(x0.x, a0.x, sA); sA = fmaf(x0.y, a0.y, sA);          \
            sA = fmaf(x0.z, a0.z, sA); sA = fmaf(x0.w, a0.w, sA);          \
            sA = fmaf(x1.x, a1.x, sA); sA = fmaf(x1.y, a1.y, sA);          \
            sA = fmaf(x1.z, a1.z, sA); sA = fmaf(x1.w, a1.w, sA);          \
            sB = fmaf(x0.x, b0.x, sB); sB = fmaf(x0.y, b0.y, sB);          \
            sB = fmaf(x0.z, b0.z, sB); sB = fmaf(x0.w, b0.w, sB);          \
            sB = fmaf(x1.x, b1.x, sB); sB = fmaf(x1.y, b1.y, sB);          \
            sB = fmaf(x1.z, b1.z, sB); sB = fmaf(x1.w, b1.w, sB);          \
            accA[j][e] = sA; accB[j][e] = sB;                              \
        }                                                                  \
    } }

    #pragma unroll 1
    for (int h = 0; h < 2; ++h) {
        const int kbase = h * KH;
        __syncthreads();                       // all reads of prev half done
        {
            const float* srcF = Wfc + (size_t)wrb * KD + kbase + scol;   // i = 0..7
            const float* srcN = Wns + (size_t)wrb * KD + kbase + scol;   // i = 8..15
            #pragma unroll
            for (int i = 0; i < 8; ++i)
                gload_lds16(srcF + (size_t)(2 * i) * KD, lds + i * 2048 + tid * 4);
            #pragma unroll
            for (int i = 0; i < 8; ++i)
                gload_lds16(srcN + (size_t)(2 * i) * KD, lds + (8 + i) * 2048 + tid * 4);
        }
        __syncthreads();                       // W-half staged (vmcnt drained)

        const float* wp0 = lds + (eq * 4) * KH + seg * 8;        // Wfc rows
        const float* wp1 = lds + (16 + eq * 4) * KH + seg * 8;   // Wns rows
        const float* xh  = xb + kbase;

        // ---- 16 tiles, zero barriers, explicit 1-tile x lookahead ----
        XLOAD(xvA, 0)
        #pragma unroll 1
        for (int t = 0; t < TPH; t += 2) {
            XLOAD(xvB, t + 1)            // next x in flight under these FMAs
            COMPUTE(xvA, t)
            if (t + 2 < TPH) XLOAD(xvA, t + 2)
            COMPUTE(xvB, t + 1)
        }
    }
#undef XLOAD
#undef COMPUTE

    // ---- butterfly over the 8 k-segs (masks 1,2,4 stay within seg-group) ----
    #pragma unroll
    for (int j = 0; j < 4; ++j)
        #pragma unroll
        for (int e = 0; e < 4; ++e) {
            float a = accA[j][e], b = accB[j][e];
            a += __shfl_xor(a, 1); a += __shfl_xor(a, 2); a += __shfl_xor(a, 4);
            b += __shfl_xor(b, 1); b += __shfl_xor(b, 2); b += __shfl_xor(b, 4);
            accA[j][e] = a; accB[j][e] = b;
        }

    __syncthreads();                  // all W reads done
    float* const slab = lds + 32 * KH;   // [64 rows][stride 33]

    if (seg == 0) {                   // each wave owns complete (row, e-quartet) outs
        #pragma unroll
        for (int j = 0; j < 4; ++j) {
            float* dst = slab + (rh * 32 + rgrp * 4 + j) * 33 + eq * 4;
            #pragma unroll
            for (int e = 0; e < 4; ++e) { dst[e] = accA[j][e]; dst[16 + e] = accB[j][e]; }
        }
    }
    __syncthreads();

    // ---- per-row epilogue: softplus noise, top-2, sparse softmax ----
    if (tid < ROWS_PER_BLK) {
        const int r = tid;
        const float* rowp = slab + r * 33;
        const size_t grow = (size_t)blockIdx.x * ROWS_PER_BLK + r;
        const float* nzp = noise + grow * NE;

        float m1 = -1e30f, m2 = -1e30f;
        int i1 = 0, i2 = 0;
        #pragma unroll
        for (int j = 0; j < NE; ++j) {
            const float z  = rowp[16 + j] + bns[j];
            const float sp = fmaxf(z, 0.f) + log1pf(expf(-fabsf(z)));  // jax softplus
            const float v  = fmaf(nzp[j], sp, rowp[j] + bfc[j]);
            if (v > m1)      { m2 = m1; i2 = i1; m1 = v; i1 = j; }     // ties -> lower idx
            else if (v > m2) { m2 = v;  i2 = j; }
        }
        const float e2  = expf(m2 - m1);
        const float inv = 1.f / (1.f + e2);

        float* po = out + grow * NE;
        #pragma unroll
        for (int j = 0; j < NE; ++j) {
            po[j] = (j == i1) ? inv : ((j == i2) ? e2 * inv : 0.f);
        }
        float* pi = out + (size_t)NROWS * NE + grow * 2;
        pi[0] = (float)i1;
        pi[1] = (float)i2;
    }
}

extern "C" void kernel_launch(void* const* d_in, const int* in_sizes, int n_in,
                              void* d_out, int out_size, void* d_ws, size_t ws_size,
                              hipStream_t stream)
{
    const float* x     = (const float*)d_in[0];
    const float* noise = (const float*)d_in[1];
    const float* Wfc   = (const float*)d_in[2];
    const float* bfc   = (const float*)d_in[3];
    const float* Wns   = (const float*)d_in[4];
    const float* bns   = (const float*)d_in[5];
    float* out = (float*)d_out;

    noisy_router_kernel<<<NROWS / ROWS_PER_BLK, 512, 0, stream>>>(
        x, noise, Wfc, bfc, Wns, bns, out);
}